// Round 2
// baseline (353.912 us; speedup 1.0000x reference)
//
#include <hip/hip_runtime.h>
#include <hip/hip_bf16.h>

using bf16 = __hip_bfloat16;
typedef __attribute__((ext_vector_type(8))) __bf16 bf16x8;
typedef __attribute__((ext_vector_type(4))) float f32x4;

#define MFMA16(a, b, c) __builtin_amdgcn_mfma_f32_16x16x32_bf16((a), (b), (c), 0, 0, 0)

static __device__ __forceinline__ void gload_lds16(const bf16* g, bf16* l) {
    __builtin_amdgcn_global_load_lds(
        (__attribute__((address_space(1))) void*)(bf16*)(g),
        (__attribute__((address_space(3))) void*)(l), 16, 0, 0);
}

// ---------------------------------------------------------------- convert
__global__ void cvt_f32_bf16(const float* __restrict__ in, bf16* __restrict__ out, int n4) {
    int i = blockIdx.x * 256 + threadIdx.x;
    if (i >= n4) return;
    float4 v = ((const float4*)in)[i];
    bf16 t[4];
    t[0] = __float2bfloat16(v.x);
    t[1] = __float2bfloat16(v.y);
    t[2] = __float2bfloat16(v.z);
    t[3] = __float2bfloat16(v.w);
    *(uint2*)(out + 4l * i) = *(uint2*)t;
}

// ---------------------------------------------------------------- GEMM1: qkv = x @ Wqkv^T + b, scatter to Q,K,V^T (bf16)
// A [M=8192][K=1024], B [N=3072][K=1024], both row-major bf16 (B^T GEMM form)
__global__ void gemm_qkv(const bf16* __restrict__ A, const bf16* __restrict__ B,
                         const float* __restrict__ bias,
                         bf16* __restrict__ Qo, bf16* __restrict__ Ko, bf16* __restrict__ Vt) {
    const int K = 1024;
    __shared__ bf16 Alds[128 * 32];
    __shared__ bf16 Blds[128 * 32];
    int t = threadIdx.x;
    int lane = t & 63;
    int wave = t >> 6;
    int wm = wave >> 1, wn = wave & 1;
    int r = lane & 15, q = lane >> 4;
    long m0 = (long)blockIdx.y * 128;
    long n0 = (long)blockIdx.x * 128;
    const bf16* Ab = A + m0 * K;
    const bf16* Bb = B + n0 * K;

    f32x4 acc[4][4] = {};

    int srow = t >> 2;           // 0..63
    int scol = (t & 3) << 3;     // 0,8,16,24

    for (int k0 = 0; k0 < K; k0 += 32) {
        __syncthreads();
        gload_lds16(Ab + (long)srow * K + k0 + scol, Alds + t * 8);
        gload_lds16(Ab + (long)(srow + 64) * K + k0 + scol, Alds + 2048 + t * 8);
        gload_lds16(Bb + (long)srow * K + k0 + scol, Blds + t * 8);
        gload_lds16(Bb + (long)(srow + 64) * K + k0 + scol, Blds + 2048 + t * 8);
        __syncthreads();  // drains vmcnt(0): LDS data visible

        bf16x8 af[4], bfv[4];
#pragma unroll
        for (int mi = 0; mi < 4; mi++)
            af[mi] = *(const bf16x8*)(Alds + (wm * 64 + mi * 16 + r) * 32 + q * 8);
#pragma unroll
        for (int ni = 0; ni < 4; ni++)
            bfv[ni] = *(const bf16x8*)(Blds + (wn * 64 + ni * 16 + r) * 32 + q * 8);
#pragma unroll
        for (int mi = 0; mi < 4; mi++)
#pragma unroll
            for (int ni = 0; ni < 4; ni++)
                acc[mi][ni] = MFMA16(af[mi], bfv[ni], acc[mi][ni]);
    }

    // epilogue: C row m = x-row (b*2048+row), col n in [0,3072): h=n/192, part=(n%192)/64, d=n%64
#pragma unroll
    for (int ni = 0; ni < 4; ni++) {
        int n = (int)n0 + wn * 64 + ni * 16 + r;
        float bn = bias[n];
        int h = n / 192;
        int rem = n % 192;
        int part = rem >> 6;
        int d = rem & 63;
#pragma unroll
        for (int mi = 0; mi < 4; mi++) {
#pragma unroll
            for (int rr = 0; rr < 4; rr++) {
                int m = (int)m0 + wm * 64 + mi * 16 + q * 4 + rr;
                int b = m >> 11;
                int row = m & 2047;
                long bh = b * 16 + h;
                bf16 bv = __float2bfloat16(acc[mi][ni][rr] + bn);
                if (part == 0)      Qo[(bh * 2048 + row) * 64 + d] = bv;
                else if (part == 1) Ko[(bh * 2048 + row) * 64 + d] = bv;
                else                Vt[(bh * 64 + d) * 2048 + row] = bv;
            }
        }
    }
}

// ---------------------------------------------------------------- attention (flash, per (bh, qtile))
// Q,K: [BH][2048][64] bf16 ; Vt: [BH][64][2048] bf16 ; AO: [B][2048][1024] bf16
__global__ void attn_fwd(const bf16* __restrict__ Q, const bf16* __restrict__ Kg,
                         const bf16* __restrict__ Vt, bf16* __restrict__ AO) {
    __shared__ bf16 Klds[64 * 64];       // [kv][d], XOR-swizzled 16B blocks
    __shared__ bf16 Vlds[64 * 64];       // [d][kv], XOR-swizzled
    __shared__ bf16 Plds[4][16 * 64];    // per-wave [qrow][kv], XOR-swizzled
    int t = threadIdx.x, lane = t & 63, wave = t >> 6;
    int r = lane & 15, c4 = lane >> 4;
    int qt = blockIdx.x, bh = blockIdx.y;
    const float C1 = 0.18033688011112042f;  // log2(e) / sqrt(64)

    const bf16* Qh = Q + ((long)bh * 2048 + qt * 64 + wave * 16) * 64;
    bf16x8 qf0 = *(const bf16x8*)(Qh + r * 64 + c4 * 8);
    bf16x8 qf1 = *(const bf16x8*)(Qh + r * 64 + 32 + c4 * 8);

    const bf16* Kh = Kg + (long)bh * 2048 * 64;
    const bf16* Vh = Vt + (long)bh * 64 * 2048;

    f32x4 acc[4] = {};
    float mrow[4] = {-1e30f, -1e30f, -1e30f, -1e30f};
    float lrow[4] = {0.f, 0.f, 0.f, 0.f};

    for (int kv0 = 0; kv0 < 2048; kv0 += 64) {
        __syncthreads();
        // stage K tile (contiguous 8KB) and Vt tile (64 rows x 128B) with 16B-block XOR swizzle
#pragma unroll
        for (int c = 0; c < 2; ++c) {
            int idx = c * 256 + t;
            int row = idx >> 3;
            int blk = idx & 7;
            int sb = blk ^ (row & 7);
            *(int4*)(Klds + row * 64 + sb * 8) = *(const int4*)(Kh + (long)kv0 * 64 + idx * 8);
            *(int4*)(Vlds + row * 64 + sb * 8) = *(const int4*)(Vh + (long)row * 2048 + kv0 + blk * 8);
        }
        __syncthreads();

        // S = Q K^T  (D layout: row=c4*4+rr is q-row, col=l&15 within group g is kv)
        f32x4 s[4];
#pragma unroll
        for (int g = 0; g < 4; ++g) {
            int krow = g * 16 + r;
            bf16x8 kf0 = *(const bf16x8*)(Klds + krow * 64 + ((c4 ^ (krow & 7)) << 3));
            bf16x8 kf1 = *(const bf16x8*)(Klds + krow * 64 + (((4 + c4) ^ (krow & 7)) << 3));
            f32x4 z = {0.f, 0.f, 0.f, 0.f};
            z = MFMA16(qf0, kf0, z);
            z = MFMA16(qf1, kf1, z);
            s[g] = z;
        }
        // online softmax (raw-logit domain; 1/8 scale folded into C1)
#pragma unroll
        for (int rr = 0; rr < 4; ++rr) {
            float v = fmaxf(fmaxf(s[0][rr], s[1][rr]), fmaxf(s[2][rr], s[3][rr]));
            v = fmaxf(v, __shfl_xor(v, 1));
            v = fmaxf(v, __shfl_xor(v, 2));
            v = fmaxf(v, __shfl_xor(v, 4));
            v = fmaxf(v, __shfl_xor(v, 8));
            float mn = fmaxf(mrow[rr], v);
            float al = exp2f((mrow[rr] - mn) * C1);
            mrow[rr] = mn;
            float sum = 0.f;
#pragma unroll
            for (int g = 0; g < 4; ++g) {
                float p = exp2f((s[g][rr] - mn) * C1);
                s[g][rr] = p;
                sum += p;
            }
            sum += __shfl_xor(sum, 1);
            sum += __shfl_xor(sum, 2);
            sum += __shfl_xor(sum, 4);
            sum += __shfl_xor(sum, 8);
            lrow[rr] = lrow[rr] * al + sum;
#pragma unroll
            for (int dg = 0; dg < 4; ++dg) acc[dg][rr] *= al;
        }
        // P -> per-wave LDS (bf16, swizzled); same-wave write->read, compiler inserts lgkmcnt
        bf16* Pw = Plds[wave];
#pragma unroll
        for (int g = 0; g < 4; ++g) {
#pragma unroll
            for (int rr = 0; rr < 4; ++rr) {
                int prow = c4 * 4 + rr;
                int pcol = g * 16 + r;
                int sb = (pcol >> 3) ^ (prow & 7);
                Pw[prow * 64 + (sb << 3) + (pcol & 7)] = __float2bfloat16(s[g][rr]);
            }
        }
        // O += P V  (A = P rows q, k contig; B = Vt rows d, k contig)
        bf16x8 pf0 = *(const bf16x8*)(Pw + r * 64 + ((c4 ^ (r & 7)) << 3));
        bf16x8 pf1 = *(const bf16x8*)(Pw + r * 64 + (((4 + c4) ^ (r & 7)) << 3));
#pragma unroll
        for (int dg = 0; dg < 4; ++dg) {
            int vrow = dg * 16 + r;
            bf16x8 vf0 = *(const bf16x8*)(Vlds + vrow * 64 + ((c4 ^ (vrow & 7)) << 3));
            bf16x8 vf1 = *(const bf16x8*)(Vlds + vrow * 64 + (((4 + c4) ^ (vrow & 7)) << 3));
            acc[dg] = MFMA16(pf0, vf0, acc[dg]);
            acc[dg] = MFMA16(pf1, vf1, acc[dg]);
        }
    }
    // epilogue: AO[b][qrow][h*64 + d]
    long b = bh >> 4;
    long h = bh & 15;
#pragma unroll
    for (int dg = 0; dg < 4; ++dg) {
#pragma unroll
        for (int rr = 0; rr < 4; ++rr) {
            long qrow = (long)qt * 64 + wave * 16 + c4 * 4 + rr;
            float o = acc[dg][rr] / lrow[rr];
            AO[(b * 2048 + qrow) * 1024 + h * 64 + dg * 16 + r] = __float2bfloat16(o);
        }
    }
}

// ---------------------------------------------------------------- GEMM2: out = AO @ Wo^T + bo (fp32 out)
__global__ void gemm_out(const bf16* __restrict__ A, const bf16* __restrict__ B,
                         const float* __restrict__ bias, float* __restrict__ C) {
    const int K = 1024, N = 1024;
    __shared__ bf16 Alds[128 * 32];
    __shared__ bf16 Blds[128 * 32];
    int t = threadIdx.x;
    int lane = t & 63;
    int wave = t >> 6;
    int wm = wave >> 1, wn = wave & 1;
    int r = lane & 15, q = lane >> 4;
    long m0 = (long)blockIdx.y * 128;
    long n0 = (long)blockIdx.x * 128;
    const bf16* Ab = A + m0 * K;
    const bf16* Bb = B + n0 * K;

    f32x4 acc[4][4] = {};

    int srow = t >> 2;
    int scol = (t & 3) << 3;

    for (int k0 = 0; k0 < K; k0 += 32) {
        __syncthreads();
        gload_lds16(Ab + (long)srow * K + k0 + scol, Alds + t * 8);
        gload_lds16(Ab + (long)(srow + 64) * K + k0 + scol, Alds + 2048 + t * 8);
        gload_lds16(Bb + (long)srow * K + k0 + scol, Blds + t * 8);
        gload_lds16(Bb + (long)(srow + 64) * K + k0 + scol, Blds + 2048 + t * 8);
        __syncthreads();

        bf16x8 af[4], bfv[4];
#pragma unroll
        for (int mi = 0; mi < 4; mi++)
            af[mi] = *(const bf16x8*)(Alds + (wm * 64 + mi * 16 + r) * 32 + q * 8);
#pragma unroll
        for (int ni = 0; ni < 4; ni++)
            bfv[ni] = *(const bf16x8*)(Blds + (wn * 64 + ni * 16 + r) * 32 + q * 8);
#pragma unroll
        for (int mi = 0; mi < 4; mi++)
#pragma unroll
            for (int ni = 0; ni < 4; ni++)
                acc[mi][ni] = MFMA16(af[mi], bfv[ni], acc[mi][ni]);
    }

#pragma unroll
    for (int ni = 0; ni < 4; ni++) {
        int n = (int)n0 + wn * 64 + ni * 16 + r;
        float bn = bias[n];
#pragma unroll
        for (int mi = 0; mi < 4; mi++) {
#pragma unroll
            for (int rr = 0; rr < 4; rr++) {
                long m = m0 + wm * 64 + mi * 16 + q * 4 + rr;
                C[m * N + n] = acc[mi][ni][rr] + bn;
            }
        }
    }
}

// ---------------------------------------------------------------- launch
extern "C" void kernel_launch(void* const* d_in, const int* in_sizes, int n_in,
                              void* d_out, int out_size, void* d_ws, size_t ws_size,
                              hipStream_t stream) {
    const float* x    = (const float*)d_in[0];  // [4,2048,1024]
    const float* Wqkv = (const float*)d_in[1];  // [3072,1024]
    const float* bqkv = (const float*)d_in[2];  // [3072]
    const float* Wo   = (const float*)d_in[3];  // [1024,1024]
    const float* bo   = (const float*)d_in[4];  // [1024]
    float* out = (float*)d_out;                 // [4,2048,1024]

    char* ws = (char*)d_ws;
    bf16* Xb  = (bf16*)(ws + 0);           // 8192*1024  = 16 MB
    bf16* Wqb = (bf16*)(ws + 16777216);    // 3072*1024  = 6 MB
    bf16* Wob = (bf16*)(ws + 23068672);    // 1024*1024  = 2 MB
    bf16* Qb  = (bf16*)(ws + 25165824);    // [64][2048][64] = 16 MB
    bf16* Kb  = (bf16*)(ws + 41943040);    // 16 MB
    bf16* Vtb = (bf16*)(ws + 58720256);    // [64][64][2048] = 16 MB
    bf16* AOb = (bf16*)(ws + 75497472);    // [8192][1024]   = 16 MB

    cvt_f32_bf16<<<8192, 256, 0, stream>>>(x, Xb, 8192 * 1024 / 4);
    cvt_f32_bf16<<<3072, 256, 0, stream>>>(Wqkv, Wqb, 3072 * 1024 / 4);
    cvt_f32_bf16<<<1024, 256, 0, stream>>>(Wo, Wob, 1024 * 1024 / 4);

    gemm_qkv<<<dim3(24, 64), 256, 0, stream>>>(Xb, Wqb, bqkv, Qb, Kb, Vtb);
    attn_fwd<<<dim3(32, 64), 256, 0, stream>>>(Qb, Kb, Vtb, AOb);
    gemm_out<<<dim3(8, 64), 256, 0, stream>>>(AOb, Wob, bo, out);
}